// Round 1
// baseline (152.763 us; speedup 1.0000x reference)
//
#include <hip/hip_runtime.h>

// ANI feature kernel: B=256 rows of N=24 atoms, T=4 types, KR=16 radial,
// KA=32 angular features. One wave (64 lanes) per (b,i) row.

constexpr int CB = 256;   // batch
constexpr int CN = 24;    // atoms
constexpr int CKR = 16;
constexpr int CKA = 32;
constexpr int NN = 23;    // neighbors per atom
constexpr int NP = 253;   // unordered neighbor pairs = 23*22/2
constexpr int KOUT = CKR + CKA;  // 48

__global__ __launch_bounds__(256) void ani_kernel(
    const float* __restrict__ coords, const int* __restrict__ atom_types,
    const float* __restrict__ EtaR, const float* __restrict__ ShfR,
    const float* __restrict__ Zeta, const float* __restrict__ ShfZ,
    const float* __restrict__ EtaA, const float* __restrict__ ShfA,
    float* __restrict__ out)
{
    __shared__ float s_rx[4][NN], s_ry[4][NN], s_rz[4][NN];
    __shared__ float s_d [4][NN], s_fA[4][NN], s_fR[4][NN];
    __shared__ unsigned char s_pa[NP], s_pb[NP];

    const int wv   = threadIdx.x >> 6;
    const int lane = threadIdx.x & 63;
    const int row  = blockIdx.x * 4 + wv;   // = b*N + i
    const int b    = row / CN;
    const int i    = row - b * CN;

    // ---- pair index table (triu_indices(23, k=1) ordering) ----
    for (int p = threadIdx.x; p < NP; p += 256) {
        int a = 0, pp = p;
        while (pp >= (NN - 1 - a)) { pp -= (NN - 1 - a); ++a; }
        s_pa[p] = (unsigned char)a;
        s_pb[p] = (unsigned char)(a + 1 + pp);
    }

    // ---- stage rij, dij, cutoffs for this row's 23 neighbors ----
    const float cix = coords[row*3+0], ciy = coords[row*3+1], ciz = coords[row*3+2];
    if (lane < NN) {
        const int j   = lane + (lane >= i ? 1 : 0);   // _NIDX[i][lane]
        const int idx = (b * CN + j) * 3;
        const float dx = cix - coords[idx+0];
        const float dy = ciy - coords[idx+1];
        const float dz = ciz - coords[idx+2];
        const float d  = sqrtf(dx*dx + dy*dy + dz*dz);
        s_rx[wv][lane] = dx; s_ry[wv][lane] = dy; s_rz[wv][lane] = dz;
        s_d [wv][lane] = d;
        s_fR[wv][lane] = 0.5f * (__cosf(d * (float)(3.14159265358979323846/5.2)) + 1.0f);
        s_fA[wv][lane] = 0.5f * (__cosf(d * (float)(3.14159265358979323846/3.5)) + 1.0f);
    }
    __syncthreads();

    const int t = atom_types[i];

    // ---- radial G2: k = lane%16, 4 j-groups reduced by shuffles ----
    {
        const int k = lane & 15, g = lane >> 4;
        const float eta = EtaR[t*CKR + k];
        const float shf = ShfR[t*CKR + k];
        float acc = 0.0f;
        for (int j = g; j < NN; j += 4) {
            const float x = s_d[wv][j] - shf;
            acc += __expf(-eta * x * x) * s_fR[wv][j];
        }
        acc += __shfl_xor(acc, 16, 64);
        acc += __shfl_xor(acc, 32, 64);
        if (lane < CKR) out[row * KOUT + k] = acc;
    }

    // ---- angular G3: k = lane%32, two half-waves split the 253 pairs ----
    {
        const int k = lane & 31, h = lane >> 5;
        const float zeta = Zeta[t*CKA + k];
        const float shfZ = ShfZ[t*CKA + k];
        const float etaA = EtaA[t*CKA + k];
        const float shfA = ShfA[t*CKA + k];
        const float cA = __cosf(shfA), sA = __sinf(shfA);
        float acc = 0.0f;
        for (int p = h; p < NP; p += 2) {
            const int a = s_pa[p], c = s_pb[p];
            const float d12 = s_d[wv][a], d13 = s_d[wv][c];
            const float dot = s_rx[wv][a]*s_rx[wv][c]
                            + s_ry[wv][a]*s_ry[wv][c]
                            + s_rz[wv][a]*s_rz[wv][c];
            float cosv = dot / (d12 * d13);
            cosv = fminf(fmaxf(cosv, -1.0f + 1e-7f), 1.0f - 1e-7f);
            const float sinv = sqrtf(1.0f - cosv * cosv);
            const float cosang = cosv * cA + sinv * sA;   // cos(acos(cosv) - shfA)
            const float hh = 0.5f * (1.0f + cosang);
            const float powz = exp2f(zeta * __log2f(hh)); // h^zeta
            const float x = 0.5f * (d12 + d13) - shfZ;
            acc += 2.0f * powz * __expf(-etaA * x * x) * (s_fA[wv][a] * s_fA[wv][c]);
        }
        acc += __shfl_xor(acc, 32, 64);
        if (lane < CKA) out[row * KOUT + CKR + k] = acc;
    }
}

extern "C" void kernel_launch(void* const* d_in, const int* in_sizes, int n_in,
                              void* d_out, int out_size, void* d_ws, size_t ws_size,
                              hipStream_t stream) {
    const float* coords     = (const float*)d_in[0];
    const int*   atom_types = (const int*)  d_in[1];
    const float* EtaR       = (const float*)d_in[2];
    const float* ShfR       = (const float*)d_in[3];
    const float* Zeta       = (const float*)d_in[4];
    const float* ShfZ       = (const float*)d_in[5];
    const float* EtaA       = (const float*)d_in[6];
    const float* ShfA       = (const float*)d_in[7];
    float* out = (float*)d_out;

    dim3 grid((CB * CN) / 4), block(256);
    hipLaunchKernelGGL(ani_kernel, grid, block, 0, stream,
                       coords, atom_types, EtaR, ShfR, Zeta, ShfZ, EtaA, ShfA, out);
}

// Round 2
// 88.468 us; speedup vs baseline: 1.7267x; 1.7267x over previous
//
#include <hip/hip_runtime.h>

// ANI feature kernel: B=256 rows of N=24 atoms, T=4 types, KR=16 radial,
// KA=32 angular features. One wave (64 lanes) per (b,i) row.
// Phase A: per-pair scalars computed once (253 pairs / 64 lanes).
// Phase B: k-dependent part only, fused single exp2 per (pair,k).

constexpr int CB = 256;   // batch
constexpr int CN = 24;    // atoms
constexpr int CKR = 16;
constexpr int CKA = 32;
constexpr int NN = 23;    // neighbors per atom
constexpr int NP = 253;   // unordered neighbor pairs = 23*22/2
constexpr int KOUT = CKR + CKA;  // 48
#define LOG2E 1.44269504088896340736f

__global__ __launch_bounds__(256) void ani_kernel(
    const float* __restrict__ coords, const int* __restrict__ atom_types,
    const float* __restrict__ EtaR, const float* __restrict__ ShfR,
    const float* __restrict__ Zeta, const float* __restrict__ ShfZ,
    const float* __restrict__ EtaA, const float* __restrict__ ShfA,
    float* __restrict__ out)
{
    __shared__ float s_rx[4][NN], s_ry[4][NN], s_rz[4][NN];
    __shared__ float s_d [4][NN], s_fA[4][NN], s_fR[4][NN];
    __shared__ unsigned char s_pa[NP], s_pb[NP];
    __shared__ float4 s_pair[4][NP + 1];   // {cosv, sinv, avg_d, 2*f12*f13}; [253] = 0 pad

    const int wv   = threadIdx.x >> 6;
    const int lane = threadIdx.x & 63;
    const int row  = blockIdx.x * 4 + wv;   // = b*N + i
    const int b    = row / CN;
    const int i    = row - b * CN;

    // ---- pair index table (triu_indices(23, k=1) ordering) ----
    for (int p = threadIdx.x; p < NP; p += 256) {
        int a = 0, pp = p;
        while (pp >= (NN - 1 - a)) { pp -= (NN - 1 - a); ++a; }
        s_pa[p] = (unsigned char)a;
        s_pb[p] = (unsigned char)(a + 1 + pp);
    }

    // ---- stage rij, dij, cutoffs for this row's 23 neighbors ----
    const float cix = coords[row*3+0], ciy = coords[row*3+1], ciz = coords[row*3+2];
    if (lane < NN) {
        const int j   = lane + (lane >= i ? 1 : 0);   // _NIDX[i][lane]
        const int idx = (b * CN + j) * 3;
        const float dx = cix - coords[idx+0];
        const float dy = ciy - coords[idx+1];
        const float dz = ciz - coords[idx+2];
        const float d  = __builtin_amdgcn_sqrtf(dx*dx + dy*dy + dz*dz);
        s_rx[wv][lane] = dx; s_ry[wv][lane] = dy; s_rz[wv][lane] = dz;
        s_d [wv][lane] = d;
        s_fR[wv][lane] = 0.5f * (__cosf(d * (float)(3.14159265358979323846/5.2)) + 1.0f);
        s_fA[wv][lane] = 0.5f * (__cosf(d * (float)(3.14159265358979323846/3.5)) + 1.0f);
    }
    __syncthreads();

    // ---- Phase A: per-pair scalars, once per pair ----
    #pragma unroll
    for (int it = 0; it < 4; ++it) {
        const int p = lane + it * 64;
        if (p < NP) {
            const int a = s_pa[p], c = s_pb[p];
            const float d12 = s_d[wv][a], d13 = s_d[wv][c];
            const float dot = s_rx[wv][a]*s_rx[wv][c]
                            + s_ry[wv][a]*s_ry[wv][c]
                            + s_rz[wv][a]*s_rz[wv][c];
            float cosv = dot * __builtin_amdgcn_rcpf(d12 * d13);
            cosv = fminf(fmaxf(cosv, -1.0f + 1e-7f), 1.0f - 1e-7f);
            const float sinv = __builtin_amdgcn_sqrtf(1.0f - cosv * cosv);
            const float avg  = 0.5f * (d12 + d13);
            const float ff2  = 2.0f * s_fA[wv][a] * s_fA[wv][c];
            s_pair[wv][p] = make_float4(cosv, sinv, avg, ff2);
        } else if (p == NP) {
            s_pair[wv][NP] = make_float4(0.0f, 0.0f, 0.0f, 0.0f);  // pad: ff2=0 -> term 0
        }
    }

    const int t = atom_types[i];

    // ---- radial G2: k = lane%16, 4 j-groups reduced by shuffles ----
    {
        const int k = lane & 15, g = lane >> 4;
        const float eta = EtaR[t*CKR + k];
        const float shf = ShfR[t*CKR + k];
        float acc = 0.0f;
        for (int j = g; j < NN; j += 4) {
            const float x = s_d[wv][j] - shf;
            acc += __builtin_amdgcn_exp2f(-(eta * LOG2E) * x * x) * s_fR[wv][j];
        }
        acc += __shfl_xor(acc, 16, 64);
        acc += __shfl_xor(acc, 32, 64);
        if (lane < CKR) out[row * KOUT + k] = acc;
    }

    __syncthreads();  // s_pair[wv] written by whole wave, read cross-lane below

    // ---- Phase B: angular G3, k = lane%32, two half-waves split the pairs ----
    {
        const int k = lane & 31, h = lane >> 5;
        const float zeta  = Zeta[t*CKA + k];
        const float shfZ  = ShfZ[t*CKA + k];
        const float etaAl = EtaA[t*CKA + k] * LOG2E;   // fold log2(e) into eta
        const float shfA  = ShfA[t*CKA + k];
        const float cA = __cosf(shfA), sA = __sinf(shfA);
        const float4* __restrict__ prow = &s_pair[wv][0];
        float acc = 0.0f;
        int p = h;
        #pragma unroll 4
        for (int it = 0; it < 127; ++it) {
            const float4 pd = prow[p]; p += 2;
            const float cosang = pd.x * cA + pd.y * sA;     // cos(acos(c) - shfA)
            const float hh  = 0.5f * cosang + 0.5f;         // (1+cosang)/2
            const float l2h = __log2f(hh);
            const float x   = pd.z - shfZ;
            const float e   = zeta * l2h - etaAl * x * x;   // log2(h^z * exp(-eta x^2))
            acc += pd.w * __builtin_amdgcn_exp2f(e);
        }
        acc += __shfl_xor(acc, 32, 64);
        if (lane < CKA) out[row * KOUT + CKR + k] = acc;
    }
}

extern "C" void kernel_launch(void* const* d_in, const int* in_sizes, int n_in,
                              void* d_out, int out_size, void* d_ws, size_t ws_size,
                              hipStream_t stream) {
    const float* coords     = (const float*)d_in[0];
    const int*   atom_types = (const int*)  d_in[1];
    const float* EtaR       = (const float*)d_in[2];
    const float* ShfR       = (const float*)d_in[3];
    const float* Zeta       = (const float*)d_in[4];
    const float* ShfZ       = (const float*)d_in[5];
    const float* EtaA       = (const float*)d_in[6];
    const float* ShfA       = (const float*)d_in[7];
    float* out = (float*)d_out;

    dim3 grid((CB * CN) / 4), block(256);
    hipLaunchKernelGGL(ani_kernel, grid, block, 0, stream,
                       coords, atom_types, EtaR, ShfR, Zeta, ShfZ, EtaA, ShfA, out);
}

// Round 3
// 78.837 us; speedup vs baseline: 1.9377x; 1.1222x over previous
//
#include <hip/hip_runtime.h>

// ANI feature kernel: B=256 rows of N=24 atoms, T=4 types, KR=16 radial,
// KA=32 angular features. One wave (64 lanes) per (b,i) row.
// Phase A: per-pair scalars once. Phase B (fast path): factorized k-grid —
// term(k)=ff2*P_a*G_z with a=k>>3 (4 angular shifts), z=k&7 (8 radial shifts);
// lanes own pairs, 32 accumulators/lane, shfl butterfly reduction.
// Generic fallback if the parameter structure check fails.

constexpr int CB = 256;   // batch
constexpr int CN = 24;    // atoms
constexpr int CKR = 16;
constexpr int CKA = 32;
constexpr int NN = 23;    // neighbors per atom
constexpr int NP = 253;   // unordered neighbor pairs = 23*22/2
constexpr int NPpad = 256;
constexpr int KOUT = CKR + CKA;  // 48
#define LOG2E 1.44269504088896340736f

template<int MASK, int BIT, int HALF>
__device__ inline void red_level(float* acc, int lane) {
    const bool hi = (lane >> BIT) & 1;
#pragma unroll
    for (int j = 0; j < HALF; ++j) {
        float send = hi ? acc[j] : acc[j + HALF];
        float recv = __shfl_xor(send, MASK, 64);
        float keep = hi ? acc[j + HALF] : acc[j];
        acc[j] = keep + recv;
    }
}

__global__ __launch_bounds__(256) void ani_kernel(
    const float* __restrict__ coords, const int* __restrict__ atom_types,
    const float* __restrict__ EtaR, const float* __restrict__ ShfR,
    const float* __restrict__ Zeta, const float* __restrict__ ShfZ,
    const float* __restrict__ EtaA, const float* __restrict__ ShfA,
    float* __restrict__ out)
{
    __shared__ float s_rx[4][NN], s_ry[4][NN], s_rz[4][NN];
    __shared__ float s_d [4][NN], s_inv[4][NN], s_fA[4][NN], s_fR[4][NN];
    __shared__ unsigned char s_pa[NP], s_pb[NP];
    __shared__ float4 s_pair[4][NPpad];   // {cosv, sinv, avg_d, 2*f12*f13}; tail zeroed

    const int wv   = threadIdx.x >> 6;
    const int lane = threadIdx.x & 63;
    const int row  = blockIdx.x * 4 + wv;   // = b*N + i
    const int b    = row / CN;
    const int i    = row - b * CN;

    // ---- pair index table (triu_indices(23, k=1) ordering) ----
    for (int p = threadIdx.x; p < NP; p += 256) {
        int a = 0, pp = p;
        while (pp >= (NN - 1 - a)) { pp -= (NN - 1 - a); ++a; }
        s_pa[p] = (unsigned char)a;
        s_pb[p] = (unsigned char)(a + 1 + pp);
    }

    // ---- stage rij, dij, 1/d, cutoffs for this row's 23 neighbors ----
    const float cix = coords[row*3+0], ciy = coords[row*3+1], ciz = coords[row*3+2];
    if (lane < NN) {
        const int j   = lane + (lane >= i ? 1 : 0);   // _NIDX[i][lane]
        const int idx = (b * CN + j) * 3;
        const float dx = cix - coords[idx+0];
        const float dy = ciy - coords[idx+1];
        const float dz = ciz - coords[idx+2];
        const float d  = __builtin_amdgcn_sqrtf(dx*dx + dy*dy + dz*dz);
        s_rx[wv][lane] = dx; s_ry[wv][lane] = dy; s_rz[wv][lane] = dz;
        s_d  [wv][lane] = d;
        s_inv[wv][lane] = __builtin_amdgcn_rcpf(d);
        s_fR[wv][lane] = 0.5f * (__cosf(d * (float)(3.14159265358979323846/5.2)) + 1.0f);
        s_fA[wv][lane] = 0.5f * (__cosf(d * (float)(3.14159265358979323846/3.5)) + 1.0f);
    }
    __syncthreads();

    // ---- Phase A: per-pair scalars, once per pair ----
    #pragma unroll
    for (int it = 0; it < 4; ++it) {
        const int p = lane + it * 64;
        if (p < NP) {
            const int a = s_pa[p], c = s_pb[p];
            const float d12 = s_d[wv][a], d13 = s_d[wv][c];
            const float dot = s_rx[wv][a]*s_rx[wv][c]
                            + s_ry[wv][a]*s_ry[wv][c]
                            + s_rz[wv][a]*s_rz[wv][c];
            float cosv = dot * (s_inv[wv][a] * s_inv[wv][c]);
            cosv = fminf(fmaxf(cosv, -1.0f + 1e-7f), 1.0f - 1e-7f);
            const float sinv = __builtin_amdgcn_sqrtf(1.0f - cosv * cosv);
            const float avg  = 0.5f * (d12 + d13);
            const float ff2  = 2.0f * s_fA[wv][a] * s_fA[wv][c];
            s_pair[wv][p] = make_float4(cosv, sinv, avg, ff2);
        } else {
            s_pair[wv][p] = make_float4(0.0f, 0.0f, 0.0f, 0.0f);  // ff2=0 -> term 0
        }
    }

    const int t = atom_types[i];

    // ---- radial G2: k = lane%16, 4 j-groups reduced by shuffles ----
    {
        const int k = lane & 15, g = lane >> 4;
        const float eta = EtaR[t*CKR + k] * LOG2E;
        const float shf = ShfR[t*CKR + k];
        float acc = 0.0f;
        for (int j = g; j < NN; j += 4) {
            const float x = s_d[wv][j] - shf;
            acc += __builtin_amdgcn_exp2f(-eta * x * x) * s_fR[wv][j];
        }
        acc += __shfl_xor(acc, 16, 64);
        acc += __shfl_xor(acc, 32, 64);
        if (lane < CKR) out[row * KOUT + k] = acc;
    }

    __syncthreads();  // s_pair[wv] written by whole wave, read cross-lane below

    // ---- structure check for the factorized fast path (wave-uniform) ----
    const float* __restrict__ Zt = ShfZ + t*CKA;
    const float* __restrict__ At = ShfA + t*CKA;
    const int kk = lane & 31;
    const bool okl = (Zeta[t*CKA + kk] == 32.0f)
                  && (EtaA[t*CKA + kk] == EtaA[t*CKA])
                  && (Zt[kk] == Zt[kk & 7])
                  && (At[kk] == At[kk & 24]);
    const bool fast = __all(okl);

    if (fast) {
        // ---- Phase B fast: lanes own pairs, factorized P_a x G_z ----
        const float cgau = -EtaA[t*CKA] * LOG2E;   // -etaA * log2(e)
        float Zv[8], cAv[4], sAv[4];
        #pragma unroll
        for (int z = 0; z < 8; ++z) Zv[z] = Zt[z];
        #pragma unroll
        for (int a = 0; a < 4; ++a) {
            const float sh = At[a * 8];
            cAv[a] = __cosf(sh); sAv[a] = __sinf(sh);
        }
        float acc[32];
        #pragma unroll
        for (int k = 0; k < 32; ++k) acc[k] = 0.0f;

        const float4* __restrict__ prow = &s_pair[wv][0];
        #pragma unroll
        for (int it = 0; it < 4; ++it) {
            const float4 pd = prow[lane + it * 64];
            float G[8];
            #pragma unroll
            for (int z = 0; z < 8; ++z) {
                const float x = pd.z - Zv[z];
                G[z] = __builtin_amdgcn_exp2f(cgau * x * x);
            }
            #pragma unroll
            for (int a = 0; a < 4; ++a) {
                const float cosang = pd.x * cAv[a] + pd.y * sAv[a];
                const float hh  = 0.5f * cosang + 0.5f;      // in [0,1]
                const float h2 = hh*hh, h4 = h2*h2, h8 = h4*h4, h16 = h8*h8;
                const float Pa = (h16 * h16) * pd.w;         // 2*ff*h^32
                #pragma unroll
                for (int z = 0; z < 8; ++z)
                    acc[a*8 + z] = fmaf(Pa, G[z], acc[a*8 + z]);
            }
        }

        // ---- reduce acc[32] across 64 lanes: 5 split levels + final add ----
        red_level<1, 0, 16>(acc, lane);
        red_level<2, 1,  8>(acc, lane);
        red_level<4, 2,  4>(acc, lane);
        red_level<8, 3,  2>(acc, lane);
        red_level<16, 4, 1>(acc, lane);
        acc[0] += __shfl_xor(acc[0], 32, 64);
        if (lane < 32) {
            const int k = ((lane & 1) << 4) | ((lane & 2) << 2) | (lane & 4)
                        | ((lane & 8) >> 2) | ((lane & 16) >> 4);
            out[row * KOUT + CKR + k] = acc[0];
        }
    } else {
        // ---- Phase B generic fallback: k = lane%32, half-waves split pairs ----
        const int k = lane & 31, h = lane >> 5;
        const float zeta  = Zeta[t*CKA + k];
        const float shfZ  = Zt[k];
        const float etaAl = EtaA[t*CKA + k] * LOG2E;
        const float shfA  = At[k];
        const float cA = __cosf(shfA), sA = __sinf(shfA);
        const float4* __restrict__ prow = &s_pair[wv][0];
        float acc = 0.0f;
        int p = h;
        #pragma unroll 4
        for (int it = 0; it < 127; ++it) {
            const float4 pd = prow[p]; p += 2;
            const float cosang = pd.x * cA + pd.y * sA;
            const float hh  = 0.5f * cosang + 0.5f;
            const float l2h = __log2f(hh);
            const float x   = pd.z - shfZ;
            const float e   = zeta * l2h - etaAl * x * x;
            acc += pd.w * __builtin_amdgcn_exp2f(e);
        }
        acc += __shfl_xor(acc, 32, 64);
        if (lane < CKA) out[row * KOUT + CKR + k] = acc;
    }
}

extern "C" void kernel_launch(void* const* d_in, const int* in_sizes, int n_in,
                              void* d_out, int out_size, void* d_ws, size_t ws_size,
                              hipStream_t stream) {
    const float* coords     = (const float*)d_in[0];
    const int*   atom_types = (const int*)  d_in[1];
    const float* EtaR       = (const float*)d_in[2];
    const float* ShfR       = (const float*)d_in[3];
    const float* Zeta       = (const float*)d_in[4];
    const float* ShfZ       = (const float*)d_in[5];
    const float* EtaA       = (const float*)d_in[6];
    const float* ShfA       = (const float*)d_in[7];
    float* out = (float*)d_out;

    dim3 grid((CB * CN) / 4), block(256);
    hipLaunchKernelGGL(ani_kernel, grid, block, 0, stream,
                       coords, atom_types, EtaR, ShfR, Zeta, ShfZ, EtaA, ShfA, out);
}

// Round 4
// 78.578 us; speedup vs baseline: 1.9441x; 1.0033x over previous
//
#include <hip/hip_runtime.h>

// ANI feature kernel: B=256 rows of N=24 atoms, T=4 types, KR=16 radial,
// KA=32 angular features. One wave (64 lanes) per (b,i) row, ZERO block
// barriers — every wave fully independent (wave-lockstep LDS for the
// 23-neighbor arrays only). Pair table is compile-time __constant__.
// Fast path: factorized k-grid term(k)=ff2*P_a*G_z (a=k>>3, z=k&7), pair
// scalars in registers, 32 accumulators/lane, shfl butterfly reduction.
// Generic fallback (recompute per pair,k) if parameter structure differs.

constexpr int CB = 256;   // batch
constexpr int CN = 24;    // atoms
constexpr int CKR = 16;
constexpr int CKA = 32;
constexpr int NN = 23;    // neighbors per atom
constexpr int NP = 253;   // unordered neighbor pairs = 23*22/2
constexpr int KOUT = CKR + CKA;  // 48
#define LOG2E 1.44269504088896340736f

struct PairTab { unsigned char pa[256]; unsigned char pb[256]; };
static constexpr PairTab make_pairs() {
    PairTab t{};
    int p = 0;
    for (int i = 0; i < NN; ++i)
        for (int j = i + 1; j < NN; ++j) {
            t.pa[p] = (unsigned char)i; t.pb[p] = (unsigned char)j; ++p;
        }
    for (; p < 256; ++p) { t.pa[p] = 0; t.pb[p] = 0; }
    return t;
}
__constant__ PairTab cPairs = make_pairs();

template<int MASK, int BIT, int HALF>
__device__ inline void red_level(float* acc, int lane) {
    const bool hi = (lane >> BIT) & 1;
#pragma unroll
    for (int j = 0; j < HALF; ++j) {
        float send = hi ? acc[j] : acc[j + HALF];
        float recv = __shfl_xor(send, MASK, 64);
        float keep = hi ? acc[j + HALF] : acc[j];
        acc[j] = keep + recv;
    }
}

__global__ __launch_bounds__(256) void ani_kernel(
    const float* __restrict__ coords, const int* __restrict__ atom_types,
    const float* __restrict__ EtaR, const float* __restrict__ ShfR,
    const float* __restrict__ Zeta, const float* __restrict__ ShfZ,
    const float* __restrict__ EtaA, const float* __restrict__ ShfA,
    float* __restrict__ out)
{
    // wave-private neighbor staging (indexed [wv] -> no cross-wave deps)
    __shared__ float s_rx[4][NN], s_ry[4][NN], s_rz[4][NN];
    __shared__ float s_d [4][NN], s_inv[4][NN], s_fA[4][NN], s_fR[4][NN];

    const int wv   = threadIdx.x >> 6;
    const int lane = threadIdx.x & 63;
    const int row  = blockIdx.x * 4 + wv;   // = b*N + i
    const int b    = row / CN;
    const int i    = row - b * CN;

    // ---- stage rij, dij, 1/d, cutoffs for this row's 23 neighbors ----
    const float cix = coords[row*3+0], ciy = coords[row*3+1], ciz = coords[row*3+2];
    if (lane < NN) {
        const int j   = lane + (lane >= i ? 1 : 0);   // _NIDX[i][lane]
        const int idx = (b * CN + j) * 3;
        const float dx = cix - coords[idx+0];
        const float dy = ciy - coords[idx+1];
        const float dz = ciz - coords[idx+2];
        const float d  = __builtin_amdgcn_sqrtf(dx*dx + dy*dy + dz*dz);
        s_rx[wv][lane] = dx; s_ry[wv][lane] = dy; s_rz[wv][lane] = dz;
        s_d  [wv][lane] = d;
        s_inv[wv][lane] = __builtin_amdgcn_rcpf(d);
        s_fR[wv][lane] = 0.5f * (__cosf(d * (float)(3.14159265358979323846/5.2)) + 1.0f);
        s_fA[wv][lane] = 0.5f * (__cosf(d * (float)(3.14159265358979323846/3.5)) + 1.0f);
    }
    // wave-lockstep: DS pipe is in-order per wave; fence compiler scheduling
    __builtin_amdgcn_wave_barrier();

    const int t = atom_types[i];

    // ---- radial G2: k = lane%16, 4 j-groups reduced by shuffles ----
    {
        const int k = lane & 15, g = lane >> 4;
        const float eta = EtaR[t*CKR + k] * LOG2E;
        const float shf = ShfR[t*CKR + k];
        float acc = 0.0f;
        for (int j = g; j < NN; j += 4) {
            const float x = s_d[wv][j] - shf;
            acc += __builtin_amdgcn_exp2f(-eta * x * x) * s_fR[wv][j];
        }
        acc += __shfl_xor(acc, 16, 64);
        acc += __shfl_xor(acc, 32, 64);
        if (lane < CKR) out[row * KOUT + k] = acc;
    }

    // ---- Phase A: per-pair scalars in REGISTERS (lane owns p = lane+64*it) ----
    float4 pd[4];
    #pragma unroll
    for (int it = 0; it < 4; ++it) {
        const int p = lane + it * 64;
        const int a = cPairs.pa[p], c = cPairs.pb[p];
        const float d12 = s_d[wv][a], d13 = s_d[wv][c];
        const float dot = s_rx[wv][a]*s_rx[wv][c]
                        + s_ry[wv][a]*s_ry[wv][c]
                        + s_rz[wv][a]*s_rz[wv][c];
        float cosv = dot * (s_inv[wv][a] * s_inv[wv][c]);
        cosv = fminf(fmaxf(cosv, -1.0f + 1e-7f), 1.0f - 1e-7f);
        const float sinv = __builtin_amdgcn_sqrtf(1.0f - cosv * cosv);
        const float avg  = 0.5f * (d12 + d13);
        const float ff2  = (p < NP) ? 2.0f * s_fA[wv][a] * s_fA[wv][c] : 0.0f;
        pd[it] = make_float4(cosv, sinv, avg, ff2);
    }

    // ---- structure check for the factorized fast path (wave-uniform) ----
    const float* __restrict__ Zt = ShfZ + t*CKA;
    const float* __restrict__ At = ShfA + t*CKA;
    const int kk = lane & 31;
    const bool okl = (Zeta[t*CKA + kk] == 32.0f)
                  && (EtaA[t*CKA + kk] == EtaA[t*CKA])
                  && (Zt[kk] == Zt[kk & 7])
                  && (At[kk] == At[kk & 24]);
    const bool fast = __all(okl);

    if (fast) {
        // ---- Phase B fast: factorized P_a x G_z on register pair data ----
        const float cgau = -EtaA[t*CKA] * LOG2E;
        float Zv[8], cAv[4], sAv[4];
        #pragma unroll
        for (int z = 0; z < 8; ++z) Zv[z] = Zt[z];
        #pragma unroll
        for (int a = 0; a < 4; ++a) {
            const float sh = At[a * 8];
            cAv[a] = __cosf(sh); sAv[a] = __sinf(sh);
        }
        float acc[32];
        #pragma unroll
        for (int k = 0; k < 32; ++k) acc[k] = 0.0f;

        #pragma unroll
        for (int it = 0; it < 4; ++it) {
            const float4 q = pd[it];
            float G[8];
            #pragma unroll
            for (int z = 0; z < 8; ++z) {
                const float x = q.z - Zv[z];
                G[z] = __builtin_amdgcn_exp2f(cgau * x * x);
            }
            #pragma unroll
            for (int a = 0; a < 4; ++a) {
                const float cosang = q.x * cAv[a] + q.y * sAv[a];
                const float hh  = 0.5f * cosang + 0.5f;      // in [0,1]
                const float h2 = hh*hh, h4 = h2*h2, h8 = h4*h4, h16 = h8*h8;
                const float Pa = (h16 * h16) * q.w;          // 2*ff*h^32
                #pragma unroll
                for (int z = 0; z < 8; ++z)
                    acc[a*8 + z] = fmaf(Pa, G[z], acc[a*8 + z]);
            }
        }

        // ---- reduce acc[32] across 64 lanes: 5 split levels + final add ----
        red_level<1, 0, 16>(acc, lane);
        red_level<2, 1,  8>(acc, lane);
        red_level<4, 2,  4>(acc, lane);
        red_level<8, 3,  2>(acc, lane);
        red_level<16, 4, 1>(acc, lane);
        acc[0] += __shfl_xor(acc[0], 32, 64);
        if (lane < 32) {
            const int k = ((lane & 1) << 4) | ((lane & 2) << 2) | (lane & 4)
                        | ((lane & 8) >> 2) | ((lane & 16) >> 4);
            out[row * KOUT + CKR + k] = acc[0];
        }
    } else {
        // ---- Phase B generic fallback: k = lane%32, half-waves split pairs,
        //      recompute pair scalars from LDS (correctness path only) ----
        const int k = lane & 31, h = lane >> 5;
        const float zeta  = Zeta[t*CKA + k];
        const float shfZ  = Zt[k];
        const float etaAl = EtaA[t*CKA + k] * LOG2E;
        const float shfA  = At[k];
        const float cA = __cosf(shfA), sA = __sinf(shfA);
        float acc = 0.0f;
        for (int p = h; p < NP; p += 2) {
            const int a = cPairs.pa[p], c = cPairs.pb[p];
            const float d12 = s_d[wv][a], d13 = s_d[wv][c];
            const float dot = s_rx[wv][a]*s_rx[wv][c]
                            + s_ry[wv][a]*s_ry[wv][c]
                            + s_rz[wv][a]*s_rz[wv][c];
            float cosv = dot * (s_inv[wv][a] * s_inv[wv][c]);
            cosv = fminf(fmaxf(cosv, -1.0f + 1e-7f), 1.0f - 1e-7f);
            const float sinv = __builtin_amdgcn_sqrtf(1.0f - cosv * cosv);
            const float cosang = cosv * cA + sinv * sA;
            const float hh  = 0.5f * cosang + 0.5f;
            const float l2h = __log2f(hh);
            const float x   = 0.5f * (d12 + d13) - shfZ;
            const float e   = zeta * l2h - etaAl * x * x;
            acc += (2.0f * s_fA[wv][a] * s_fA[wv][c]) * __builtin_amdgcn_exp2f(e);
        }
        acc += __shfl_xor(acc, 32, 64);
        if (lane < CKA) out[row * KOUT + CKR + k] = acc;
    }
}

extern "C" void kernel_launch(void* const* d_in, const int* in_sizes, int n_in,
                              void* d_out, int out_size, void* d_ws, size_t ws_size,
                              hipStream_t stream) {
    const float* coords     = (const float*)d_in[0];
    const int*   atom_types = (const int*)  d_in[1];
    const float* EtaR       = (const float*)d_in[2];
    const float* ShfR       = (const float*)d_in[3];
    const float* Zeta       = (const float*)d_in[4];
    const float* ShfZ       = (const float*)d_in[5];
    const float* EtaA       = (const float*)d_in[6];
    const float* ShfA       = (const float*)d_in[7];
    float* out = (float*)d_out;

    dim3 grid((CB * CN) / 4), block(256);
    hipLaunchKernelGGL(ani_kernel, grid, block, 0, stream,
                       coords, atom_types, EtaR, ShfR, Zeta, ShfZ, EtaA, ShfA, out);
}

// Round 5
// 78.490 us; speedup vs baseline: 1.9463x; 1.0011x over previous
//
#include <hip/hip_runtime.h>

// ANI feature kernel, molecule-tiled: grid=512 blocks (2 blocks per molecule),
// block=256 (4 waves), each wave computes 3 center atoms (512*4*3 = 6144 rows).
// Block stages the molecule's 24x24 distance matrix + rcp + cutoffs in LDS ONCE
// (law of cosines kills the need for rij vectors). Fast path: factorized k-grid
// term(k)=ff2*P_a*G_z (a=k>>3, z=k&7), 32 accumulators/lane, shfl butterfly.
// Generic fallback per center if parameter structure differs.

constexpr int CB = 256;   // batch (molecules)
constexpr int CN = 24;    // atoms
constexpr int CKR = 16;
constexpr int CKA = 32;
constexpr int NN = 23;    // neighbors per center
constexpr int NP = 253;   // unordered neighbor pairs
constexpr int KOUT = CKR + CKA;  // 48
constexpr int LDM = 25;   // LDS leading dim for 24x24 (stride pad)
#define LOG2E 1.44269504088896340736f

struct PairTab { unsigned char pa[256]; unsigned char pb[256]; };
static constexpr PairTab make_pairs() {
    PairTab t{};
    int p = 0;
    for (int i = 0; i < NN; ++i)
        for (int j = i + 1; j < NN; ++j) {
            t.pa[p] = (unsigned char)i; t.pb[p] = (unsigned char)j; ++p;
        }
    for (; p < 256; ++p) { t.pa[p] = 0; t.pb[p] = 0; }
    return t;
}
__constant__ PairTab cPairs = make_pairs();

template<int MASK, int BIT, int HALF>
__device__ inline void red_level(float* acc, int lane) {
    const bool hi = (lane >> BIT) & 1;
#pragma unroll
    for (int j = 0; j < HALF; ++j) {
        float send = hi ? acc[j] : acc[j + HALF];
        float recv = __shfl_xor(send, MASK, 64);
        float keep = hi ? acc[j + HALF] : acc[j];
        acc[j] = keep + recv;
    }
}

__global__ __launch_bounds__(256) void ani_kernel(
    const float* __restrict__ coords, const int* __restrict__ atom_types,
    const float* __restrict__ EtaR, const float* __restrict__ ShfR,
    const float* __restrict__ Zeta, const float* __restrict__ ShfZ,
    const float* __restrict__ EtaA, const float* __restrict__ ShfA,
    float* __restrict__ out)
{
    __shared__ float sc[CN][3];                 // molecule coords
    __shared__ float sD [CN*LDM];               // d(j,k)
    __shared__ float sI [CN*LDM];               // 1/d(j,k)
    __shared__ float sFA[CN*LDM];               // angular cutoff f(d; 3.5)
    __shared__ float sFR[CN*LDM];               // radial  cutoff f(d; 5.2)

    const int tid  = threadIdx.x;
    const int wv   = tid >> 6;
    const int lane = tid & 63;
    const int m    = blockIdx.x >> 1;           // molecule
    const int h    = blockIdx.x & 1;            // which half of the centers

    // ---- stage molecule coords into LDS ----
    if (tid < CN * 3) sc[tid / 3][tid % 3] = coords[m * CN * 3 + tid];
    __syncthreads();

    // ---- 24x24 geometry, once per block ----
    for (int p = tid; p < CN * CN; p += 256) {
        const int j = p / CN, k = p - j * CN;
        const float dx = sc[j][0] - sc[k][0];
        const float dy = sc[j][1] - sc[k][1];
        const float dz = sc[j][2] - sc[k][2];
        const float d  = __builtin_amdgcn_sqrtf(dx*dx + dy*dy + dz*dz);
        const int o = j * LDM + k;
        sD [o] = d;
        sI [o] = __builtin_amdgcn_rcpf(d);      // inf on diagonal, never used
        sFA[o] = 0.5f * (__cosf(d * (float)(3.14159265358979323846/3.5)) + 1.0f);
        sFR[o] = 0.5f * (__cosf(d * (float)(3.14159265358979323846/5.2)) + 1.0f);
    }
    __syncthreads();

    // ---- each wave: 3 centers ----
    #pragma unroll 1
    for (int r = 0; r < 3; ++r) {
        const int i   = h * 12 + wv * 3 + r;    // center atom
        const int row = m * CN + i;
        const int t   = atom_types[i];
        const int i25 = i * LDM;

        // ---- radial G2: k = lane%16, 4 neighbor groups, shuffle reduce ----
        {
            const int k = lane & 15, g = lane >> 4;
            const float eta = EtaR[t*CKR + k] * LOG2E;
            const float shf = ShfR[t*CKR + k];
            float acc = 0.0f;
            for (int n = g; n < NN; n += 4) {
                const int j = n + (n >= i ? 1 : 0);
                const float x = sD[i25 + j] - shf;
                acc += __builtin_amdgcn_exp2f(-eta * x * x) * sFR[i25 + j];
            }
            acc += __shfl_xor(acc, 16, 64);
            acc += __shfl_xor(acc, 32, 64);
            if (lane < CKR) out[row * KOUT + k] = acc;
        }

        // ---- Phase A: per-pair scalars via law of cosines (registers) ----
        float4 pd[4];
        #pragma unroll
        for (int it = 0; it < 4; ++it) {
            const int p  = lane + it * 64;
            const int n1 = cPairs.pa[p], n2 = cPairs.pb[p];
            const int j  = n1 + (n1 >= i ? 1 : 0);
            const int k2 = n2 + (n2 >= i ? 1 : 0);
            const float d12 = sD[i25 + j],  d13 = sD[i25 + k2];
            const float djk = sD[j * LDM + k2];
            const float i12 = sI[i25 + j],  i13 = sI[i25 + k2];
            float cosv = (d12*d12 + d13*d13 - djk*djk) * (0.5f * i12 * i13);
            cosv = fminf(fmaxf(cosv, -1.0f + 1e-7f), 1.0f - 1e-7f); // also scrubs NaN
            const float sinv = __builtin_amdgcn_sqrtf(1.0f - cosv * cosv);
            const float avg  = 0.5f * (d12 + d13);
            const float ff2  = (p < NP) ? 2.0f * sFA[i25 + j] * sFA[i25 + k2] : 0.0f;
            pd[it] = make_float4(cosv, sinv, avg, ff2);
        }

        // ---- structure check for the factorized fast path (wave-uniform) ----
        const float* __restrict__ Zt = ShfZ + t*CKA;
        const float* __restrict__ At = ShfA + t*CKA;
        const int kk = lane & 31;
        const bool okl = (Zeta[t*CKA + kk] == 32.0f)
                      && (EtaA[t*CKA + kk] == EtaA[t*CKA])
                      && (Zt[kk] == Zt[kk & 7])
                      && (At[kk] == At[kk & 24]);
        const bool fast = __all(okl);

        if (fast) {
            const float cgau = -EtaA[t*CKA] * LOG2E;
            float Zv[8], cAv[4], sAv[4];
            #pragma unroll
            for (int z = 0; z < 8; ++z) Zv[z] = Zt[z];
            #pragma unroll
            for (int a = 0; a < 4; ++a) {
                const float sh = At[a * 8];
                cAv[a] = __cosf(sh); sAv[a] = __sinf(sh);
            }
            float acc[32];
            #pragma unroll
            for (int k = 0; k < 32; ++k) acc[k] = 0.0f;

            #pragma unroll
            for (int it = 0; it < 4; ++it) {
                const float4 q = pd[it];
                float G[8];
                #pragma unroll
                for (int z = 0; z < 8; ++z) {
                    const float x = q.z - Zv[z];
                    G[z] = __builtin_amdgcn_exp2f(cgau * x * x);
                }
                #pragma unroll
                for (int a = 0; a < 4; ++a) {
                    const float cosang = q.x * cAv[a] + q.y * sAv[a];
                    const float hh  = 0.5f * cosang + 0.5f;      // in [0,1]
                    const float h2 = hh*hh, h4 = h2*h2, h8 = h4*h4, h16 = h8*h8;
                    const float Pa = (h16 * h16) * q.w;          // 2*ff*h^32
                    #pragma unroll
                    for (int z = 0; z < 8; ++z)
                        acc[a*8 + z] = fmaf(Pa, G[z], acc[a*8 + z]);
                }
            }

            red_level<1, 0, 16>(acc, lane);
            red_level<2, 1,  8>(acc, lane);
            red_level<4, 2,  4>(acc, lane);
            red_level<8, 3,  2>(acc, lane);
            red_level<16, 4, 1>(acc, lane);
            acc[0] += __shfl_xor(acc[0], 32, 64);
            if (lane < 32) {
                const int k = ((lane & 1) << 4) | ((lane & 2) << 2) | (lane & 4)
                            | ((lane & 8) >> 2) | ((lane & 16) >> 4);
                out[row * KOUT + CKR + k] = acc[0];
            }
        } else {
            // ---- generic fallback: k = lane%32, half-waves split pairs ----
            const int k = lane & 31, hh2 = lane >> 5;
            const float zeta  = Zeta[t*CKA + k];
            const float shfZ  = Zt[k];
            const float etaAl = EtaA[t*CKA + k] * LOG2E;
            const float shfA  = At[k];
            const float cA = __cosf(shfA), sA = __sinf(shfA);
            float acc = 0.0f;
            for (int p = hh2; p < NP; p += 2) {
                const int n1 = cPairs.pa[p], n2 = cPairs.pb[p];
                const int j  = n1 + (n1 >= i ? 1 : 0);
                const int k2 = n2 + (n2 >= i ? 1 : 0);
                const float d12 = sD[i25 + j],  d13 = sD[i25 + k2];
                const float djk = sD[j * LDM + k2];
                const float i12 = sI[i25 + j],  i13 = sI[i25 + k2];
                float cosv = (d12*d12 + d13*d13 - djk*djk) * (0.5f * i12 * i13);
                cosv = fminf(fmaxf(cosv, -1.0f + 1e-7f), 1.0f - 1e-7f);
                const float sinv = __builtin_amdgcn_sqrtf(1.0f - cosv * cosv);
                const float cosang = cosv * cA + sinv * sA;
                const float hhp = 0.5f * cosang + 0.5f;
                const float l2h = __log2f(hhp);
                const float x   = 0.5f * (d12 + d13) - shfZ;
                const float e   = zeta * l2h - etaAl * x * x;
                acc += (2.0f * sFA[i25 + j] * sFA[i25 + k2]) * __builtin_amdgcn_exp2f(e);
            }
            acc += __shfl_xor(acc, 32, 64);
            if (lane < CKA) out[row * KOUT + CKR + k] = acc;
        }
    }
}

extern "C" void kernel_launch(void* const* d_in, const int* in_sizes, int n_in,
                              void* d_out, int out_size, void* d_ws, size_t ws_size,
                              hipStream_t stream) {
    const float* coords     = (const float*)d_in[0];
    const int*   atom_types = (const int*)  d_in[1];
    const float* EtaR       = (const float*)d_in[2];
    const float* ShfR       = (const float*)d_in[3];
    const float* Zeta       = (const float*)d_in[4];
    const float* ShfZ       = (const float*)d_in[5];
    const float* EtaA       = (const float*)d_in[6];
    const float* ShfA       = (const float*)d_in[7];
    float* out = (float*)d_out;

    dim3 grid(CB * 2), block(256);   // 2 blocks per molecule, 3 centers per wave
    hipLaunchKernelGGL(ani_kernel, grid, block, 0, stream,
                       coords, atom_types, EtaR, ShfR, Zeta, ShfZ, EtaA, ShfA, out);
}